// Round 6
// baseline (261.319 us; speedup 1.0000x reference)
//
#include <hip/hip_runtime.h>
#include <math.h>

#define DIM_ 512
#define HID_ 2048
#define B_ 8
#define N_ 1024
#define ROWS_ 8192   // B_*N_
#define TOPK 16      // exact: gate at rank>=16 is <= e^-54 (k<12), contribution ~1e-20

typedef __attribute__((ext_vector_type(8))) short short8;
typedef __attribute__((ext_vector_type(4))) float float4v;

__device__ __forceinline__ float sigm(float x) { return 1.f / (1.f + __expf(-x)); }

__device__ __forceinline__ short f2bf(float f) {           // RNE fp32 -> bf16
    unsigned u = __float_as_uint(f);
    u += 0x7FFF + ((u >> 16) & 1);
    return (short)(u >> 16);
}

__device__ __forceinline__ float bf2f(unsigned short s) {
    return __uint_as_float((unsigned)s << 16);
}

__device__ __forceinline__ unsigned f2ord(float f) {       // monotone fp32 -> u32
    unsigned u = __float_as_uint(f);
    return (u & 0x80000000u) ? ~u : (u | 0x80000000u);
}
__device__ __forceinline__ float ord2f(unsigned o) {
    unsigned u = (o & 0x80000000u) ? (o & 0x7FFFFFFFu) : ~o;
    return __uint_as_float(u);
}

__device__ __forceinline__ void gload16(const short* g, short* l) {
    __builtin_amdgcn_global_load_lds(
        (const __attribute__((address_space(1))) void*)g,
        (__attribute__((address_space(3))) void*)l, 16, 0, 0);
}

// ---------------- fp32 -> bf16 conversion ----------------
__global__ __launch_bounds__(256)
void cvt_bf16_kernel(const float* __restrict__ in, short* __restrict__ out, int n4) {
    const int i = blockIdx.x * 256 + threadIdx.x;
    if (i < n4) {
        const float4 v = *(const float4*)(in + (long long)i * 4);
        short4 o;
        o.x = f2bf(v.x); o.y = f2bf(v.y); o.z = f2bf(v.z); o.w = f2bf(v.w);
        *(short4*)(out + (long long)i * 4) = o;
    }
}

// ---------------- pooled = mean over N ----------------
__global__ __launch_bounds__(512)
void pool_part_kernel(const float* __restrict__ x, float* __restrict__ part) {
    const int bx = blockIdx.x;
    const int b = bx >> 5, chunk = bx & 31;
    const int c = threadIdx.x;                     // 512
    const float* xb = x + ((long long)b * N_ + chunk * 32) * DIM_ + c;
    float s = 0.f;
    for (int n = 0; n < 32; ++n) s += xb[(long long)n * DIM_];
    part[(long long)bx * DIM_ + c] = s;
}

__global__ __launch_bounds__(512)
void pool_reduce_kernel(const float* __restrict__ part, float* __restrict__ pooled) {
    const int b = blockIdx.x;
    const int c = threadIdx.x;
    float s = 0.f;
    for (int g = 0; g < 32; ++g) s += part[((long long)b * 32 + g) * DIM_ + c];
    pooled[b * DIM_ + c] = s * (1.f / 1024.f);
}

// ---------------- head nets: k_cont (B,3), w (B,3) ----------------
__global__ __launch_bounds__(128)
void heads_kernel(const float* __restrict__ pooled,
                  const float* __restrict__ k1w, const float* __restrict__ k1b,
                  const float* __restrict__ k2w, const float* __restrict__ k2b,
                  const float* __restrict__ w1w, const float* __restrict__ w1b,
                  const float* __restrict__ w2w, const float* __restrict__ w2b,
                  float* __restrict__ kcont, float* __restrict__ wbr) {
    const int b = blockIdx.x;
    const int t = threadIdx.x;                     // 128
    __shared__ float sp[DIM_];
    __shared__ float kh[128], wh[128];
    __shared__ float wraw[4];
    for (int i = t; i < DIM_; i += 128) sp[i] = pooled[b * DIM_ + i];
    __syncthreads();
    float ak = k1b[t], aw = w1b[t];
    for (int k = 0; k < DIM_; ++k) {
        float pv = sp[k];
        ak = fmaf(pv, k1w[t * DIM_ + k], ak);
        aw = fmaf(pv, w1w[t * DIM_ + k], aw);
    }
    kh[t] = fmaxf(ak, 0.f);
    wh[t] = fmaxf(aw, 0.f);
    __syncthreads();
    if (t < 3) {
        float rk = k2b[t], rw = w2b[t];
        for (int k = 0; k < 128; ++k) {
            rk = fmaf(kh[k], k2w[t * 128 + k], rk);
            rw = fmaf(wh[k], w2w[t * 128 + k], rw);
        }
        kcont[b * 3 + t] = 1.f + 11.f * sigm(rk);
        wraw[t] = rw;
    }
    __syncthreads();
    if (t == 0) {
        float m = fmaxf(wraw[0], fmaxf(wraw[1], wraw[2]));
        float e0 = __expf(wraw[0] - m), e1 = __expf(wraw[1] - m), e2 = __expf(wraw[2] - m);
        float inv = 1.f / (e0 + e1 + e2);
        wbr[b * 3 + 0] = e0 * inv;
        wbr[b * 3 + 1] = e1 * inv;
        wbr[b * 3 + 2] = e2 * inv;
    }
}

// ---------------- bf16 MFMA NT GEMM ----------------
// 128x128 tile, BK=64, 4 waves (each 64x64 = 4x4 of 16x16x32 MFMA).
// OUTMODE: 0 = bf16 out, bias+relu; 2 = fp32 raw out (no bias)
template<int OUTMODE>
__global__ __launch_bounds__(256)
void gemm_mfma(const short* __restrict__ A, const short* __restrict__ Bm,
               const float* __restrict__ bias,
               float* __restrict__ outF, short* __restrict__ outB,
               int M, int N, int K, int lda, int ldb,
               long long sA, long long sB, long long sC) {
    const int bz = blockIdx.z;
    A  += (long long)bz * sA;
    Bm += (long long)bz * sB;

    __shared__ short As[128 * 64];
    __shared__ short Bs[128 * 64];

    const int tid = threadIdx.x;
    const int lane = tid & 63;
    const int wv = tid >> 6;                // 0..3
    const int m0 = blockIdx.y * 128;
    const int n0 = blockIdx.x * 128;

    const int lrow = lane >> 3;             // 0..7
    const int cg = (lane & 7) ^ lrow;       // XOR swizzle

    const int ml = (wv & 1) * 64;
    const int nl = (wv >> 1) * 64;
    const int fr = lane & 15;
    const int kq = lane >> 4;

    float4v acc[4][4];
#pragma unroll
    for (int i = 0; i < 4; ++i)
#pragma unroll
        for (int j = 0; j < 4; ++j) acc[i][j] = (float4v){0.f, 0.f, 0.f, 0.f};

    for (int k0 = 0; k0 < K; k0 += 64) {
        __syncthreads();
#pragma unroll
        for (int i = 0; i < 4; ++i) {
            const int rloc = wv * 32 + i * 8 + lrow;
            gload16(A + (long long)(m0 + rloc) * lda + (k0 + cg * 8),
                    &As[(wv * 32 + i * 8) * 64]);
            gload16(Bm + (long long)(n0 + rloc) * ldb + (k0 + cg * 8),
                    &Bs[(wv * 32 + i * 8) * 64]);
        }
        __syncthreads();
#pragma unroll
        for (int ks = 0; ks < 2; ++ks) {
            const int c = ks * 4 + kq;
            short8 af[4], bfr[4];
#pragma unroll
            for (int i = 0; i < 4; ++i) {
                const int m = ml + i * 16 + fr;
                af[i] = *(const short8*)&As[m * 64 + ((c ^ (m & 7)) * 8)];
                const int n = nl + i * 16 + fr;
                bfr[i] = *(const short8*)&Bs[n * 64 + ((c ^ (n & 7)) * 8)];
            }
#pragma unroll
            for (int i = 0; i < 4; ++i)
#pragma unroll
                for (int j = 0; j < 4; ++j)
                    acc[i][j] = __builtin_amdgcn_mfma_f32_16x16x32_bf16(
                        af[i], bfr[j], acc[i][j], 0, 0, 0);
        }
    }

    const long long outOfs = (long long)bz * sC;
#pragma unroll
    for (int i = 0; i < 4; ++i) {
#pragma unroll
        for (int j = 0; j < 4; ++j) {
            const int ng = n0 + nl + j * 16 + fr;
            float bv = 0.f;
            if (OUTMODE != 2) bv = bias[ng];
#pragma unroll
            for (int r = 0; r < 4; ++r) {
                const int mg = m0 + ml + i * 16 + kq * 4 + r;
                float v = acc[i][j][r] + bv;
                if (OUTMODE == 0) v = fmaxf(v, 0.f);
                const long long idx = outOfs + (long long)mg * N + ng;
                if (OUTMODE == 2) outF[idx] = v;
                else              outB[idx] = f2bf(v);
            }
        }
    }
}

// ---------------- split-K combine: hb = bf16(p0 + p1 + bias) ----------------
__global__ __launch_bounds__(256)
void combine_kernel(const float* __restrict__ p0, const float* __restrict__ p1,
                    const float* __restrict__ bias, short* __restrict__ out) {
    const int i = blockIdx.x * 256 + threadIdx.x;     // over 4M/4 elements
    const long long o = (long long)i * 4;
    const float4 a = *(const float4*)(p0 + o);
    const float4 b = *(const float4*)(p1 + o);
    const int col = (int)(o & (DIM_ - 1));
    const float4 bs = *(const float4*)(bias + col);
    short4 r;
    r.x = f2bf(a.x + b.x + bs.x);
    r.y = f2bf(a.y + b.y + bs.y);
    r.z = f2bf(a.z + b.z + bs.z);
    r.w = f2bf(a.w + b.w + bs.w);
    *(short4*)(out + o) = r;
}

// ---------------- fused per-row top-16 + aggregate ----------------
// One wave per row. Merge-based exact top-16 (stable desc argsort order):
//   1) lane-local bitonic sort of 16 u64 keys (registers, no shuffles)
//   2) 6 merge rounds over lane distance d: shuffle partner's reversed list,
//      elementwise max (bitonic half-cleaner), 4-stage bitonic clean.
// After rounds, ALL lanes hold identical sorted top-16 -> compute coefs
// redundantly, then the same wave gathers h rows (bf16) into y.
__global__ __launch_bounds__(256)
void topk_agg_kernel(const float* __restrict__ sim,
                     const float* __restrict__ kcont, const float* __restrict__ wbr,
                     const unsigned short* __restrict__ h, float* __restrict__ y) {
    const int wv = threadIdx.x >> 6;
    const int lane = threadIdx.x & 63;
    const int row = blockIdx.x * 4 + wv;          // 2048 blocks * 4 waves
    const int b = row >> 10;
    const float* srow = sim + (long long)row * N_;

    float f[16];
    const int base = lane * 16;
#pragma unroll
    for (int q = 0; q < 4; ++q) {
        const float4 v = *(const float4*)(srow + base + q * 4);
        f[q * 4 + 0] = v.x; f[q * 4 + 1] = v.y; f[q * 4 + 2] = v.z; f[q * 4 + 3] = v.w;
    }

    // row max
    float lmax = f[0];
#pragma unroll
    for (int j = 1; j < 16; ++j) lmax = fmaxf(lmax, f[j]);
#pragma unroll
    for (int d = 32; d > 0; d >>= 1) lmax = fmaxf(lmax, __shfl_xor(lmax, d));
    const float maxv = lmax;

    // softmax denominator (full row)
    float lsum = 0.f;
#pragma unroll
    for (int j = 0; j < 16; ++j) lsum += __expf(f[j] - maxv);
#pragma unroll
    for (int d = 32; d > 0; d >>= 1) lsum += __shfl_xor(lsum, d);
    const float invden = 1.f / lsum;

    // u64 keys: (ord(value) << 32) | (1024 - idx) -> desc key order == stable argsort
    unsigned long long key[16];
#pragma unroll
    for (int j = 0; j < 16; ++j)
        key[j] = ((unsigned long long)f2ord(f[j]) << 32) | (unsigned)(1024 - (base + j));

    // 1) lane-local bitonic sort, descending (80 comparators, register-only)
#pragma unroll
    for (int k = 2; k <= 16; k <<= 1) {
#pragma unroll
        for (int j = k >> 1; j > 0; j >>= 1) {
#pragma unroll
            for (int i = 0; i < 16; ++i) {
                const int l = i ^ j;
                if (l > i) {
                    const bool desc = ((i & k) == 0);
                    const unsigned long long a = key[i], bk = key[l];
                    const bool sw = desc ? (a < bk) : (a > bk);
                    key[i] = sw ? bk : a;
                    key[l] = sw ? a : bk;
                }
            }
        }
    }

    // 2) 6 merge rounds: keep top-16 of (mine, partner at distance d)
#pragma unroll
    for (int d = 1; d < 64; d <<= 1) {
        unsigned long long other[16];
#pragma unroll
        for (int i = 0; i < 16; ++i)
            other[i] = __shfl_xor(key[15 - i], d);     // partner's reversed list
#pragma unroll
        for (int i = 0; i < 16; ++i)
            key[i] = (key[i] > other[i]) ? key[i] : other[i];   // half-cleaner
        // bitonic clean to descending
#pragma unroll
        for (int j = 8; j > 0; j >>= 1) {
#pragma unroll
            for (int i = 0; i < 16; ++i) {
                if ((i & j) == 0) {
                    const unsigned long long a = key[i], bk = key[i | j];
                    const bool sw = (a < bk);
                    key[i] = sw ? bk : a;
                    key[i | j] = sw ? a : bk;
                }
            }
        }
    }

    // all lanes now hold the identical sorted top-16
    const float kc0 = kcont[b * 3 + 0], kc1 = kcont[b * 3 + 1], kc2 = kcont[b * 3 + 2];
    const float w0 = wbr[b * 3 + 0], w1 = wbr[b * 3 + 1], w2 = wbr[b * 3 + 2];

    float p[16], g0[16], g1[16], g2[16];
    float s0 = 0.f, s1 = 0.f, s2 = 0.f;
#pragma unroll
    for (int r = 0; r < 16; ++r) {
        const float v = ord2f((unsigned)(key[r] >> 32));
        p[r] = __expf(v - maxv) * invden;
        const float rr = (float)r + 0.5f;
        g0[r] = sigm(12.f * (kc0 - rr));
        g1[r] = sigm(12.f * (kc1 - rr));
        g2[r] = sigm(12.f * (kc2 - rr));
        s0 = fmaf(p[r], g0[r], s0);
        s1 = fmaf(p[r], g1[r], s1);
        s2 = fmaf(p[r], g2[r], s2);
    }
    const float f0 = w0 / (s0 + 1e-8f);
    const float f1 = w1 / (s1 + 1e-8f);
    const float f2 = w2 / (s2 + 1e-8f);

    // gather-aggregate: lane covers 8 channels; 16 neighbor rows
    const unsigned short* hbase = h + (long long)b * (N_ * DIM_) + lane * 8;
    float acc[8] = {0.f, 0.f, 0.f, 0.f, 0.f, 0.f, 0.f, 0.f};
#pragma unroll
    for (int r = 0; r < 16; ++r) {
        const int idx = 1024 - (int)(key[r] & 0xFFFFFFFFu);
        const float coef = p[r] * (f0 * g0[r] + f1 * g1[r] + f2 * g2[r]);
        const ushort4 h0 = *(const ushort4*)(hbase + (long long)idx * DIM_);
        const ushort4 h1 = *(const ushort4*)(hbase + (long long)idx * DIM_ + 4);
        acc[0] = fmaf(coef, bf2f(h0.x), acc[0]);
        acc[1] = fmaf(coef, bf2f(h0.y), acc[1]);
        acc[2] = fmaf(coef, bf2f(h0.z), acc[2]);
        acc[3] = fmaf(coef, bf2f(h0.w), acc[3]);
        acc[4] = fmaf(coef, bf2f(h1.x), acc[4]);
        acc[5] = fmaf(coef, bf2f(h1.y), acc[5]);
        acc[6] = fmaf(coef, bf2f(h1.z), acc[6]);
        acc[7] = fmaf(coef, bf2f(h1.w), acc[7]);
    }
    float* yp = y + (long long)row * DIM_ + lane * 8;
    *(float4*)(yp + 0) = make_float4(acc[0], acc[1], acc[2], acc[3]);
    *(float4*)(yp + 4) = make_float4(acc[4], acc[5], acc[6], acc[7]);
}

extern "C" void kernel_launch(void* const* d_in, const int* in_sizes, int n_in,
                              void* d_out, int out_size, void* d_ws, size_t ws_size,
                              hipStream_t stream) {
    const float* x     = (const float*)d_in[0];
    const float* fc1_w = (const float*)d_in[1];
    const float* fc1_b = (const float*)d_in[2];
    const float* fc2_w = (const float*)d_in[3];
    const float* fc2_b = (const float*)d_in[4];
    const float* k1_w  = (const float*)d_in[5];
    const float* k1_b  = (const float*)d_in[6];
    const float* k2_w  = (const float*)d_in[7];
    const float* k2_b  = (const float*)d_in[8];
    const float* w1_w  = (const float*)d_in[9];
    const float* w1_b  = (const float*)d_in[10];
    const float* w2_w  = (const float*)d_in[11];
    const float* w2_b  = (const float*)d_in[12];

    char* ws = (char*)d_ws;
    // timeline-overlapped layout (single stream => sequential):
    //   [0, 33.5M):   h1b (bf16, live fc1->fc2)  then simbuf (fp32, live sim->topk)
    //   [33.5M, 67.1M): xb (bf16, live cvt->fc1) then partial0/1 (fp32, live fc2->combine)
    short* h1b    = (short*)(ws + 0);              // 33,554,432
    float* simbuf = (float*)(ws + 0);
    short* xb     = (short*)(ws + 33554432);       // 8,388,608 (dead before partials written)
    float* part0  = (float*)(ws + 33554432);       // 16,777,216
    float* part1  = (float*)(ws + 50331648);       // 16,777,216
    short* hb     = (short*)(ws + 67108864);       // 8,388,608
    short* w1b    = (short*)(ws + 75497472);       // 2,097,152
    short* w2b    = (short*)(ws + 77594624);       // 2,097,152
    float* ppart  = (float*)(ws + 79691776);       // 524,288
    float* pooled = (float*)(ws + 80216064);       // 16,384
    float* kcont  = (float*)(ws + 80232448);       // 128
    float* wbr    = (float*)(ws + 80232576);       // 128

    float* y = (float*)d_out;

    // 0) bf16 conversions
    cvt_bf16_kernel<<<dim3(ROWS_ * DIM_ / 4 / 256), dim3(256), 0, stream>>>(x, xb, ROWS_ * DIM_ / 4);
    cvt_bf16_kernel<<<dim3(HID_ * DIM_ / 4 / 256), dim3(256), 0, stream>>>(fc1_w, w1b, HID_ * DIM_ / 4);
    cvt_bf16_kernel<<<dim3(DIM_ * HID_ / 4 / 256), dim3(256), 0, stream>>>(fc2_w, w2b, DIM_ * HID_ / 4);

    // 1) pooled mean + head nets
    pool_part_kernel<<<dim3(B_ * 32), dim3(512), 0, stream>>>(x, ppart);
    pool_reduce_kernel<<<dim3(B_), dim3(512), 0, stream>>>(ppart, pooled);
    heads_kernel<<<dim3(B_), dim3(128), 0, stream>>>(pooled, k1_w, k1_b, k2_w, k2_b,
                                                     w1_w, w1_b, w2_w, w2_b, kcont, wbr);

    // 2) h1 = relu(x @ fc1_w^T + b1) -> bf16    M=8192 N=2048 K=512
    gemm_mfma<0><<<dim3(HID_ / 128, ROWS_ / 128, 1), dim3(256), 0, stream>>>(
        xb, w1b, fc1_b, nullptr, h1b, ROWS_, HID_, DIM_, DIM_, DIM_, 0, 0, 0);
    // 3) fc2 split-K=2: partial[z] = h1[:, z*1024:+1024] @ w2[:, z*1024:+1024]^T (fp32 raw)
    gemm_mfma<2><<<dim3(DIM_ / 128, ROWS_ / 128, 2), dim3(256), 0, stream>>>(
        h1b, w2b, nullptr, part0, nullptr, ROWS_, DIM_, HID_ / 2, HID_, HID_,
        (long long)(HID_ / 2), (long long)(HID_ / 2), (long long)ROWS_ * DIM_);
    //    combine: hb = bf16(p0 + p1 + bias)
    combine_kernel<<<dim3(ROWS_ * DIM_ / 4 / 256), dim3(256), 0, stream>>>(part0, part1, fc2_b, hb);
    // 4) sim[b] = hb[b] @ hb[b]^T -> fp32       M=N=1024 K=512, batch 8 (overwrites h1b)
    gemm_mfma<2><<<dim3(N_ / 128, N_ / 128, B_), dim3(256), 0, stream>>>(
        hb, hb, nullptr, simbuf, nullptr, N_, N_, DIM_, DIM_, DIM_,
        (long long)N_ * DIM_, (long long)N_ * DIM_, (long long)N_ * N_);

    // 5) fused per-row top-16 + aggregate into output
    topk_agg_kernel<<<dim3(ROWS_ / 4), dim3(256), 0, stream>>>(
        simbuf, kcont, wbr, (const unsigned short*)hb, y);
}

// Round 7
// 223.881 us; speedup vs baseline: 1.1672x; 1.1672x over previous
//
#include <hip/hip_runtime.h>
#include <math.h>

#define DIM_ 512
#define HID_ 2048
#define B_ 8
#define N_ 1024
#define ROWS_ 8192   // B_*N_
#define TOPK 16      // exact: gate at rank>=16 is <= e^-54 (k<12), contribution ~1e-20

typedef __attribute__((ext_vector_type(8))) short short8;
typedef __attribute__((ext_vector_type(4))) float float4v;

__device__ __forceinline__ float sigm(float x) { return 1.f / (1.f + __expf(-x)); }

__device__ __forceinline__ short f2bf(float f) {           // RNE fp32 -> bf16
    unsigned u = __float_as_uint(f);
    u += 0x7FFF + ((u >> 16) & 1);
    return (short)(u >> 16);
}

__device__ __forceinline__ float bf2f(unsigned short s) {
    return __uint_as_float((unsigned)s << 16);
}

__device__ __forceinline__ unsigned f2ord(float f) {       // monotone fp32 -> u32
    unsigned u = __float_as_uint(f);
    return (u & 0x80000000u) ? ~u : (u | 0x80000000u);
}

__device__ __forceinline__ void gload16(const short* g, short* l) {
    __builtin_amdgcn_global_load_lds(
        (const __attribute__((address_space(1))) void*)g,
        (__attribute__((address_space(3))) void*)l, 16, 0, 0);
}

// ---------------- both weight matrices -> bf16 (one launch) ----------------
__global__ __launch_bounds__(256)
void cvt_w_kernel(const float* __restrict__ w1, const float* __restrict__ w2,
                  short* __restrict__ o1, short* __restrict__ o2) {
    const int i = blockIdx.x * 256 + threadIdx.x;      // 0 .. 2*262144
    const int n4 = HID_ * DIM_ / 4;                    // 262144
    const float* in = (i < n4) ? w1 : w2;
    short* out = (i < n4) ? o1 : o2;
    const int j = (i < n4) ? i : (i - n4);
    const float4 v = *(const float4*)(in + (long long)j * 4);
    short4 o;
    o.x = f2bf(v.x); o.y = f2bf(v.y); o.z = f2bf(v.z); o.w = f2bf(v.w);
    *(short4*)(out + (long long)j * 4) = o;
}

// ---------------- pooled partial sums + x -> bf16 (fused) ----------------
__global__ __launch_bounds__(512)
void pool_part_cvt_kernel(const float* __restrict__ x, float* __restrict__ part,
                          short* __restrict__ xb) {
    const int bx = blockIdx.x;                     // 256
    const int b = bx >> 5, chunk = bx & 31;
    const int c = threadIdx.x;                     // 512
    const long long base = ((long long)b * N_ + chunk * 32) * DIM_ + c;
    const float* xp = x + base;
    short* xo = xb + base;
    float s = 0.f;
    for (int n = 0; n < 32; ++n) {
        const float v = xp[(long long)n * DIM_];
        s += v;
        xo[(long long)n * DIM_] = f2bf(v);
    }
    part[(long long)bx * DIM_ + c] = s;
}

// ---------------- pooled reduce + head nets (fused): k_cont (B,3), w (B,3) ----------------
__global__ __launch_bounds__(512)
void pool_heads_kernel(const float* __restrict__ part,
                       const float* __restrict__ k1w, const float* __restrict__ k1b,
                       const float* __restrict__ k2w, const float* __restrict__ k2b,
                       const float* __restrict__ w1w, const float* __restrict__ w1b,
                       const float* __restrict__ w2w, const float* __restrict__ w2b,
                       float* __restrict__ kcont, float* __restrict__ wbr) {
    const int b = blockIdx.x;
    const int t = threadIdx.x;                     // 512
    __shared__ float sp[DIM_];
    __shared__ float kh[128], wh[128];
    __shared__ float wraw[4];
    float s = 0.f;
    for (int g = 0; g < 32; ++g) s += part[((long long)b * 32 + g) * DIM_ + t];
    sp[t] = s * (1.f / 1024.f);
    __syncthreads();
    if (t < 128) {
        float ak = k1b[t], aw = w1b[t];
        for (int k = 0; k < DIM_; ++k) {
            const float pv = sp[k];
            ak = fmaf(pv, k1w[t * DIM_ + k], ak);
            aw = fmaf(pv, w1w[t * DIM_ + k], aw);
        }
        kh[t] = fmaxf(ak, 0.f);
        wh[t] = fmaxf(aw, 0.f);
    }
    __syncthreads();
    if (t < 3) {
        float rk = k2b[t], rw = w2b[t];
        for (int k = 0; k < 128; ++k) {
            rk = fmaf(kh[k], k2w[t * 128 + k], rk);
            rw = fmaf(wh[k], w2w[t * 128 + k], rw);
        }
        kcont[b * 3 + t] = 1.f + 11.f * sigm(rk);
        wraw[t] = rw;
    }
    __syncthreads();
    if (t == 0) {
        const float m = fmaxf(wraw[0], fmaxf(wraw[1], wraw[2]));
        const float e0 = __expf(wraw[0] - m), e1 = __expf(wraw[1] - m), e2 = __expf(wraw[2] - m);
        const float inv = 1.f / (e0 + e1 + e2);
        wbr[b * 3 + 0] = e0 * inv;
        wbr[b * 3 + 1] = e1 * inv;
        wbr[b * 3 + 2] = e2 * inv;
    }
}

// ---------------- bf16 MFMA NT GEMM (unchanged, verified) ----------------
// 128x128 tile, BK=64, 4 waves (each 64x64 = 4x4 of 16x16x32 MFMA).
// OUTMODE: 0 = bf16 out, bias+relu; 2 = fp32 raw out (no bias)
template<int OUTMODE>
__global__ __launch_bounds__(256)
void gemm_mfma(const short* __restrict__ A, const short* __restrict__ Bm,
               const float* __restrict__ bias,
               float* __restrict__ outF, short* __restrict__ outB,
               int M, int N, int K, int lda, int ldb,
               long long sA, long long sB, long long sC) {
    const int bz = blockIdx.z;
    A  += (long long)bz * sA;
    Bm += (long long)bz * sB;

    __shared__ short As[128 * 64];
    __shared__ short Bs[128 * 64];

    const int tid = threadIdx.x;
    const int lane = tid & 63;
    const int wv = tid >> 6;                // 0..3
    const int m0 = blockIdx.y * 128;
    const int n0 = blockIdx.x * 128;

    const int lrow = lane >> 3;             // 0..7
    const int cg = (lane & 7) ^ lrow;       // XOR swizzle

    const int ml = (wv & 1) * 64;
    const int nl = (wv >> 1) * 64;
    const int fr = lane & 15;
    const int kq = lane >> 4;

    float4v acc[4][4];
#pragma unroll
    for (int i = 0; i < 4; ++i)
#pragma unroll
        for (int j = 0; j < 4; ++j) acc[i][j] = (float4v){0.f, 0.f, 0.f, 0.f};

    for (int k0 = 0; k0 < K; k0 += 64) {
        __syncthreads();
#pragma unroll
        for (int i = 0; i < 4; ++i) {
            const int rloc = wv * 32 + i * 8 + lrow;
            gload16(A + (long long)(m0 + rloc) * lda + (k0 + cg * 8),
                    &As[(wv * 32 + i * 8) * 64]);
            gload16(Bm + (long long)(n0 + rloc) * ldb + (k0 + cg * 8),
                    &Bs[(wv * 32 + i * 8) * 64]);
        }
        __syncthreads();
#pragma unroll
        for (int ks = 0; ks < 2; ++ks) {
            const int c = ks * 4 + kq;
            short8 af[4], bfr[4];
#pragma unroll
            for (int i = 0; i < 4; ++i) {
                const int m = ml + i * 16 + fr;
                af[i] = *(const short8*)&As[m * 64 + ((c ^ (m & 7)) * 8)];
                const int n = nl + i * 16 + fr;
                bfr[i] = *(const short8*)&Bs[n * 64 + ((c ^ (n & 7)) * 8)];
            }
#pragma unroll
            for (int i = 0; i < 4; ++i)
#pragma unroll
                for (int j = 0; j < 4; ++j)
                    acc[i][j] = __builtin_amdgcn_mfma_f32_16x16x32_bf16(
                        af[i], bfr[j], acc[i][j], 0, 0, 0);
        }
    }

    const long long outOfs = (long long)bz * sC;
#pragma unroll
    for (int i = 0; i < 4; ++i) {
#pragma unroll
        for (int j = 0; j < 4; ++j) {
            const int ng = n0 + nl + j * 16 + fr;
            float bv = 0.f;
            if (OUTMODE != 2) bv = bias[ng];
#pragma unroll
            for (int r = 0; r < 4; ++r) {
                const int mg = m0 + ml + i * 16 + kq * 4 + r;
                float v = acc[i][j][r] + bv;
                if (OUTMODE == 0) v = fmaxf(v, 0.f);
                const long long idx = outOfs + (long long)mg * N + ng;
                if (OUTMODE == 2) outF[idx] = v;
                else              outB[idx] = f2bf(v);
            }
        }
    }
}

// ---------------- split-K combine: hb = bf16(p0 + p1 + bias) ----------------
__global__ __launch_bounds__(256)
void combine_kernel(const float* __restrict__ p0, const float* __restrict__ p1,
                    const float* __restrict__ bias, short* __restrict__ out) {
    const int i = blockIdx.x * 256 + threadIdx.x;
    const long long o = (long long)i * 4;
    const float4 a = *(const float4*)(p0 + o);
    const float4 b = *(const float4*)(p1 + o);
    const int col = (int)(o & (DIM_ - 1));
    const float4 bs = *(const float4*)(bias + col);
    short4 r;
    r.x = f2bf(a.x + b.x + bs.x);
    r.y = f2bf(a.y + b.y + bs.y);
    r.z = f2bf(a.z + b.z + bs.z);
    r.w = f2bf(a.w + b.w + bs.w);
    *(short4*)(out + o) = r;
}

// ---------------- fused per-row top-16 + aggregate (two-phase exact) ----------------
// Phase A: select top-16 SET with u32 keys ((ord(v)&~1023)|(1023-idx)) via
//   lane-local bitonic + 6 merge rounds. u32 comparators = v_max/v_min (2 inst).
//   Set is exact except ties within 2^-13 at the 16/17 boundary, where gate<=e^-42.
// Phase B: re-read exact fp32 for the 16 survivors, 10-stage cross-lane bitonic
//   on exact u64 keys within each 16-lane group -> exact stable rank order.
// Then per-rank coefs (butterfly s-sums) + gather h (bf16) into y.
__global__ __launch_bounds__(256)
void topk_agg_kernel(const float* __restrict__ sim,
                     const float* __restrict__ kcont, const float* __restrict__ wbr,
                     const unsigned short* __restrict__ h, float* __restrict__ y) {
    const int wv = threadIdx.x >> 6;
    const int lane = threadIdx.x & 63;
    const int ll = lane & 15;
    const int row = blockIdx.x * 4 + wv;          // 2048 blocks * 4 waves
    const int b = row >> 10;
    const float* srow = sim + (long long)row * N_;

    float f[16];
    const int base = lane * 16;
#pragma unroll
    for (int q = 0; q < 4; ++q) {
        const float4 v = *(const float4*)(srow + base + q * 4);
        f[q * 4 + 0] = v.x; f[q * 4 + 1] = v.y; f[q * 4 + 2] = v.z; f[q * 4 + 3] = v.w;
    }

    // row max
    float lmax = f[0];
#pragma unroll
    for (int j = 1; j < 16; ++j) lmax = fmaxf(lmax, f[j]);
#pragma unroll
    for (int d = 32; d > 0; d >>= 1) lmax = fmaxf(lmax, __shfl_xor(lmax, d));
    const float maxv = lmax;

    // softmax denominator (full row, exact fp32)
    float lsum = 0.f;
#pragma unroll
    for (int j = 0; j < 16; ++j) lsum += __expf(f[j] - maxv);
#pragma unroll
    for (int d = 32; d > 0; d >>= 1) lsum += __shfl_xor(lsum, d);
    const float invden = 1.f / lsum;

    // ---- Phase A: u32 keys ----
    unsigned key[16];
#pragma unroll
    for (int j = 0; j < 16; ++j)
        key[j] = (f2ord(f[j]) & 0xFFFFFC00u) | (unsigned)(1023 - (base + j));

    // lane-local bitonic sort, descending (min/max comparators)
#pragma unroll
    for (int k = 2; k <= 16; k <<= 1) {
#pragma unroll
        for (int j = k >> 1; j > 0; j >>= 1) {
#pragma unroll
            for (int i = 0; i < 16; ++i) {
                const int l = i ^ j;
                if (l > i) {
                    const bool desc = ((i & k) == 0);
                    const unsigned a = key[i], bk = key[l];
                    const unsigned hi = (a > bk) ? a : bk;
                    const unsigned lo = (a > bk) ? bk : a;
                    key[i] = desc ? hi : lo;
                    key[l] = desc ? lo : hi;
                }
            }
        }
    }

    // 6 merge rounds: keep top-16 of (mine, partner at distance d)
#pragma unroll
    for (int d = 1; d < 64; d <<= 1) {
        unsigned other[16];
#pragma unroll
        for (int i = 0; i < 16; ++i)
            other[i] = __shfl_xor(key[15 - i], d);         // 1 bpermute each
#pragma unroll
        for (int i = 0; i < 16; ++i)
            key[i] = (key[i] > other[i]) ? key[i] : other[i];
#pragma unroll
        for (int j = 8; j > 0; j >>= 1) {
#pragma unroll
            for (int i = 0; i < 16; ++i) {
                if ((i & j) == 0) {
                    const unsigned a = key[i], bk = key[i | j];
                    key[i]     = (a > bk) ? a : bk;
                    key[i | j] = (a > bk) ? bk : a;
                }
            }
        }
    }

    // ---- Phase B: exact order of the 16 survivors ----
    // pick own candidate (all lanes hold identical sorted-16)
    unsigned k32 = key[0];
#pragma unroll
    for (int j = 1; j < 16; ++j) k32 = (ll == j) ? key[j] : k32;
    const int myidx = 1023 - (int)(k32 & 1023u);
    const float myval = srow[myidx];                        // L1-hot re-read, exact fp32

    unsigned long long kx = ((unsigned long long)f2ord(myval) << 32)
                          | (unsigned)(1023 - myidx);
    // cross-lane bitonic sort of 16 (descending), replicated in each 16-lane group
#pragma unroll
    for (int k = 2; k <= 16; k <<= 1) {
#pragma unroll
        for (int d = k >> 1; d > 0; d >>= 1) {
            const unsigned long long other = __shfl_xor(kx, d);
            const bool keepMax = (((ll & k) != 0) == ((ll & d) != 0));
            const bool mineBig = (kx > other);
            kx = (keepMax == mineBig) ? kx : other;
        }
    }
    // lane ll now holds the rank-ll candidate
    const unsigned sord = (unsigned)(kx >> 32);
    const unsigned su = (sord & 0x80000000u) ? (sord & 0x7FFFFFFFu) : ~sord;
    const float sval = __uint_as_float(su);
    const int sidx = 1023 - (int)(kx & 1023u);

    const float kc0 = kcont[b * 3 + 0], kc1 = kcont[b * 3 + 1], kc2 = kcont[b * 3 + 2];
    const float w0 = wbr[b * 3 + 0], w1 = wbr[b * 3 + 1], w2 = wbr[b * 3 + 2];

    // per-rank terms (rank = ll), butterfly s-sums within the 16-group
    const float p = __expf(sval - maxv) * invden;
    const float rr = (float)ll + 0.5f;
    const float g0 = sigm(12.f * (kc0 - rr));
    const float g1 = sigm(12.f * (kc1 - rr));
    const float g2 = sigm(12.f * (kc2 - rr));
    float s0 = p * g0, s1 = p * g1, s2 = p * g2;
#pragma unroll
    for (int d = 1; d < 16; d <<= 1) {
        s0 += __shfl_xor(s0, d);
        s1 += __shfl_xor(s1, d);
        s2 += __shfl_xor(s2, d);
    }
    const float f0 = w0 / (s0 + 1e-8f);
    const float f1 = w1 / (s1 + 1e-8f);
    const float f2 = w2 / (s2 + 1e-8f);
    const float mycoef = p * (f0 * g0 + f1 * g1 + f2 * g2);

    // distribute (idx, coef) of all 16 ranks to every lane, then gather
    const int gbase = lane & 48;
    const unsigned short* hbase = h + (long long)b * (N_ * DIM_) + lane * 8;
    float acc[8] = {0.f, 0.f, 0.f, 0.f, 0.f, 0.f, 0.f, 0.f};
#pragma unroll
    for (int r = 0; r < 16; ++r) {
        const float coef = __shfl(mycoef, gbase | r);
        const int idx = __shfl(sidx, gbase | r);
        const ushort4 h0 = *(const ushort4*)(hbase + (long long)idx * DIM_);
        const ushort4 h1 = *(const ushort4*)(hbase + (long long)idx * DIM_ + 4);
        acc[0] = fmaf(coef, bf2f(h0.x), acc[0]);
        acc[1] = fmaf(coef, bf2f(h0.y), acc[1]);
        acc[2] = fmaf(coef, bf2f(h0.z), acc[2]);
        acc[3] = fmaf(coef, bf2f(h0.w), acc[3]);
        acc[4] = fmaf(coef, bf2f(h1.x), acc[4]);
        acc[5] = fmaf(coef, bf2f(h1.y), acc[5]);
        acc[6] = fmaf(coef, bf2f(h1.z), acc[6]);
        acc[7] = fmaf(coef, bf2f(h1.w), acc[7]);
    }
    float* yp = y + (long long)row * DIM_ + lane * 8;
    *(float4*)(yp + 0) = make_float4(acc[0], acc[1], acc[2], acc[3]);
    *(float4*)(yp + 4) = make_float4(acc[4], acc[5], acc[6], acc[7]);
}

extern "C" void kernel_launch(void* const* d_in, const int* in_sizes, int n_in,
                              void* d_out, int out_size, void* d_ws, size_t ws_size,
                              hipStream_t stream) {
    const float* x     = (const float*)d_in[0];
    const float* fc1_w = (const float*)d_in[1];
    const float* fc1_b = (const float*)d_in[2];
    const float* fc2_w = (const float*)d_in[3];
    const float* fc2_b = (const float*)d_in[4];
    const float* k1_w  = (const float*)d_in[5];
    const float* k1_b  = (const float*)d_in[6];
    const float* k2_w  = (const float*)d_in[7];
    const float* k2_b  = (const float*)d_in[8];
    const float* w1_w  = (const float*)d_in[9];
    const float* w1_b  = (const float*)d_in[10];
    const float* w2_w  = (const float*)d_in[11];
    const float* w2_b  = (const float*)d_in[12];

    char* ws = (char*)d_ws;
    short* h1b    = (short*)(ws + 0);              // 33,554,432
    float* simbuf = (float*)(ws + 0);              // reuse after fc2
    short* xb     = (short*)(ws + 33554432);       // 8,388,608 (dead before partials written)
    float* part0  = (float*)(ws + 33554432);       // 16,777,216
    float* part1  = (float*)(ws + 50331648);       // 16,777,216
    short* hb     = (short*)(ws + 67108864);       // 8,388,608
    short* w1b    = (short*)(ws + 75497472);       // 2,097,152
    short* w2b    = (short*)(ws + 77594624);       // 2,097,152
    float* ppart  = (float*)(ws + 79691776);       // 524,288
    float* kcont  = (float*)(ws + 80216064);       // 128
    float* wbr    = (float*)(ws + 80216192);       // 128

    float* y = (float*)d_out;

    // 0) weights -> bf16 (one launch)
    cvt_w_kernel<<<dim3(2 * HID_ * DIM_ / 4 / 256), dim3(256), 0, stream>>>(fc1_w, fc2_w, w1b, w2b);
    // 1) pooled partials + x -> bf16 (fused)
    pool_part_cvt_kernel<<<dim3(B_ * 32), dim3(512), 0, stream>>>(x, ppart, xb);
    // 2) pooled reduce + head nets (fused)
    pool_heads_kernel<<<dim3(B_), dim3(512), 0, stream>>>(ppart, k1_w, k1_b, k2_w, k2_b,
                                                          w1_w, w1_b, w2_w, w2_b, kcont, wbr);
    // 3) h1 = relu(x @ fc1_w^T + b1) -> bf16    M=8192 N=2048 K=512
    gemm_mfma<0><<<dim3(HID_ / 128, ROWS_ / 128, 1), dim3(256), 0, stream>>>(
        xb, w1b, fc1_b, nullptr, h1b, ROWS_, HID_, DIM_, DIM_, DIM_, 0, 0, 0);
    // 4) fc2 split-K=2: partial[z] = h1[:, z*1024:+1024] @ w2[:, z*1024:+1024]^T (fp32 raw)
    gemm_mfma<2><<<dim3(DIM_ / 128, ROWS_ / 128, 2), dim3(256), 0, stream>>>(
        h1b, w2b, nullptr, part0, nullptr, ROWS_, DIM_, HID_ / 2, HID_, HID_,
        (long long)(HID_ / 2), (long long)(HID_ / 2), (long long)ROWS_ * DIM_);
    //    combine: hb = bf16(p0 + p1 + bias)
    combine_kernel<<<dim3(ROWS_ * DIM_ / 4 / 256), dim3(256), 0, stream>>>(part0, part1, fc2_b, hb);
    // 5) sim[b] = hb[b] @ hb[b]^T -> fp32       M=N=1024 K=512, batch 8 (overwrites h1b)
    gemm_mfma<2><<<dim3(N_ / 128, N_ / 128, B_), dim3(256), 0, stream>>>(
        hb, hb, nullptr, simbuf, nullptr, N_, N_, DIM_, DIM_, DIM_,
        (long long)N_ * DIM_, (long long)N_ * DIM_, (long long)N_ * N_);
    // 6) fused per-row top-16 + aggregate into output
    topk_agg_kernel<<<dim3(ROWS_ / 4), dim3(256), 0, stream>>>(
        simbuf, kcont, wbr, (const unsigned short*)hb, y);
}

// Round 8
// 221.152 us; speedup vs baseline: 1.1816x; 1.0123x over previous
//
#include <hip/hip_runtime.h>
#include <math.h>

#define DIM_ 512
#define HID_ 2048
#define B_ 8
#define N_ 1024
#define ROWS_ 8192   // B_*N_
#define TOPK 16      // exact: gate at rank>=16 is <= e^-54 (k<12), contribution ~1e-20

typedef __attribute__((ext_vector_type(8))) short short8;
typedef __attribute__((ext_vector_type(16))) float float16v;

__device__ __forceinline__ float sigm(float x) { return 1.f / (1.f + __expf(-x)); }

__device__ __forceinline__ short f2bf(float f) {           // RNE fp32 -> bf16
    unsigned u = __float_as_uint(f);
    u += 0x7FFF + ((u >> 16) & 1);
    return (short)(u >> 16);
}

__device__ __forceinline__ float bf2f(unsigned short s) {
    return __uint_as_float((unsigned)s << 16);
}

__device__ __forceinline__ unsigned f2ord(float f) {       // monotone fp32 -> u32
    unsigned u = __float_as_uint(f);
    return (u & 0x80000000u) ? ~u : (u | 0x80000000u);
}

__device__ __forceinline__ void gload16(const short* g, short* l) {
    __builtin_amdgcn_global_load_lds(
        (const __attribute__((address_space(1))) void*)g,
        (__attribute__((address_space(3))) void*)l, 16, 0, 0);
}

// ---------------- fused prep: pooled partials + x->bf16  |  weights->bf16 ----------------
__global__ __launch_bounds__(512)
void prep_kernel(const float* __restrict__ x, float* __restrict__ part, short* __restrict__ xb,
                 const float* __restrict__ w1, const float* __restrict__ w2,
                 short* __restrict__ o1, short* __restrict__ o2) {
    const int bx = blockIdx.x;
    if (bx < 256) {
        const int b = bx >> 5, chunk = bx & 31;
        const int c = threadIdx.x;                     // 512
        const long long base = ((long long)b * N_ + chunk * 32) * DIM_ + c;
        const float* xp = x + base;
        short* xo = xb + base;
        float s = 0.f;
        for (int n = 0; n < 32; ++n) {
            const float v = xp[(long long)n * DIM_];
            s += v;
            xo[(long long)n * DIM_] = f2bf(v);
        }
        part[(long long)bx * DIM_ + c] = s;
    } else {
        const int n4 = HID_ * DIM_ / 4;                // 262144 float4 per matrix
        int i = (bx - 256) * 2048 + threadIdx.x;
#pragma unroll
        for (int t = 0; t < 4; ++t, i += 512) {
            const float* in = (i < n4) ? w1 : w2;
            short* out = (i < n4) ? o1 : o2;
            const int j = (i < n4) ? i : (i - n4);
            const float4 v = *(const float4*)(in + (long long)j * 4);
            short4 o;
            o.x = f2bf(v.x); o.y = f2bf(v.y); o.z = f2bf(v.z); o.w = f2bf(v.w);
            *(short4*)(out + (long long)j * 4) = o;
        }
    }
}

// ---------------- pooled reduce + head nets (fused): k_cont (B,3), w (B,3) ----------------
__global__ __launch_bounds__(512)
void pool_heads_kernel(const float* __restrict__ part,
                       const float* __restrict__ k1w, const float* __restrict__ k1b,
                       const float* __restrict__ k2w, const float* __restrict__ k2b,
                       const float* __restrict__ w1w, const float* __restrict__ w1b,
                       const float* __restrict__ w2w, const float* __restrict__ w2b,
                       float* __restrict__ kcont, float* __restrict__ wbr) {
    const int b = blockIdx.x;
    const int t = threadIdx.x;                     // 512
    __shared__ float sp[DIM_];
    __shared__ float kh[128], wh[128];
    __shared__ float wraw[4];
    float s = 0.f;
    for (int g = 0; g < 32; ++g) s += part[((long long)b * 32 + g) * DIM_ + t];
    sp[t] = s * (1.f / 1024.f);
    __syncthreads();
    if (t < 128) {
        float ak = k1b[t], aw = w1b[t];
        for (int k = 0; k < DIM_; ++k) {
            const float pv = sp[k];
            ak = fmaf(pv, k1w[t * DIM_ + k], ak);
            aw = fmaf(pv, w1w[t * DIM_ + k], aw);
        }
        kh[t] = fmaxf(ak, 0.f);
        wh[t] = fmaxf(aw, 0.f);
    }
    __syncthreads();
    if (t < 3) {
        float rk = k2b[t], rw = w2b[t];
        for (int k = 0; k < 128; ++k) {
            rk = fmaf(kh[k], k2w[t * 128 + k], rk);
            rw = fmaf(wh[k], w2w[t * 128 + k], rw);
        }
        kcont[b * 3 + t] = 1.f + 11.f * sigm(rk);
        wraw[t] = rw;
    }
    __syncthreads();
    if (t == 0) {
        const float m = fmaxf(wraw[0], fmaxf(wraw[1], wraw[2]));
        const float e0 = __expf(wraw[0] - m), e1 = __expf(wraw[1] - m), e2 = __expf(wraw[2] - m);
        const float inv = 1.f / (e0 + e1 + e2);
        wbr[b * 3 + 0] = e0 * inv;
        wbr[b * 3 + 1] = e1 * inv;
        wbr[b * 3 + 2] = e2 * inv;
    }
}

// ---------------- bf16 MFMA NT GEMM, 32x32x16 ----------------
// 128x128 tile, BK=64, 4 waves; each wave 64x64 = 2x2 frags of 32x32x16.
// A/B frag: m|n = lane&31, k = (lane>>5)*8 + j.  C/D: col=lane&31,
// row=(reg&3)+8*(reg>>2)+4*(lane>>5)  [m74/m101-verified].
// OUTMODE: 0 = bf16 out, bias+relu; 2 = fp32 raw out (no bias)
template<int OUTMODE>
__global__ __launch_bounds__(256)
void gemm_mfma(const short* __restrict__ A, const short* __restrict__ Bm,
               const float* __restrict__ bias,
               float* __restrict__ outF, short* __restrict__ outB,
               int M, int N, int K, int lda, int ldb,
               long long sA, long long sB, long long sC) {
    const int bz = blockIdx.z;
    A  += (long long)bz * sA;
    Bm += (long long)bz * sB;

    __shared__ short As[128 * 64];
    __shared__ short Bs[128 * 64];

    const int tid = threadIdx.x;
    const int lane = tid & 63;
    const int wv = tid >> 6;                // 0..3
    const int m0 = blockIdx.y * 128;
    const int n0 = blockIdx.x * 128;

    const int lrow = lane >> 3;             // 0..7
    const int cg = (lane & 7) ^ lrow;       // XOR swizzle

    const int ml = (wv & 1) * 64;
    const int nl = (wv >> 1) * 64;
    const int fr = lane & 31;               // fragment row/col (m or n)
    const int kh = lane >> 5;               // k-half 0..1

    float16v acc[2][2];
#pragma unroll
    for (int i = 0; i < 2; ++i)
#pragma unroll
        for (int j = 0; j < 2; ++j)
#pragma unroll
            for (int r = 0; r < 16; ++r) acc[i][j][r] = 0.f;

    for (int k0 = 0; k0 < K; k0 += 64) {
        __syncthreads();
#pragma unroll
        for (int i = 0; i < 4; ++i) {
            const int rloc = wv * 32 + i * 8 + lrow;
            gload16(A + (long long)(m0 + rloc) * lda + (k0 + cg * 8),
                    &As[(wv * 32 + i * 8) * 64]);
            gload16(Bm + (long long)(n0 + rloc) * ldb + (k0 + cg * 8),
                    &Bs[(wv * 32 + i * 8) * 64]);
        }
        __syncthreads();
#pragma unroll
        for (int c = 0; c < 4; ++c) {           // 4 ksteps of K=16
            const int ch = c * 2 + kh;          // 8-elem chunk index
            short8 af[2], bfr[2];
#pragma unroll
            for (int i = 0; i < 2; ++i) {
                const int m = ml + i * 32 + fr;
                af[i] = *(const short8*)&As[m * 64 + ((ch ^ (m & 7)) * 8)];
                const int n = nl + i * 32 + fr;
                bfr[i] = *(const short8*)&Bs[n * 64 + ((ch ^ (n & 7)) * 8)];
            }
#pragma unroll
            for (int i = 0; i < 2; ++i)
#pragma unroll
                for (int j = 0; j < 2; ++j)
                    acc[i][j] = __builtin_amdgcn_mfma_f32_32x32x16_bf16(
                        af[i], bfr[j], acc[i][j], 0, 0, 0);
        }
    }

    const long long outOfs = (long long)bz * sC;
#pragma unroll
    for (int i = 0; i < 2; ++i) {
#pragma unroll
        for (int j = 0; j < 2; ++j) {
            const int ng = n0 + nl + j * 32 + fr;
            float bv = 0.f;
            if (OUTMODE != 2) bv = bias[ng];
#pragma unroll
            for (int r = 0; r < 16; ++r) {
                const int mg = m0 + ml + i * 32 + (r & 3) + 8 * (r >> 2) + 4 * kh;
                float v = acc[i][j][r] + bv;
                if (OUTMODE == 0) v = fmaxf(v, 0.f);
                const long long idx = outOfs + (long long)mg * N + ng;
                if (OUTMODE == 2) outF[idx] = v;
                else              outB[idx] = f2bf(v);
            }
        }
    }
}

// ---------------- split-K combine: hb = bf16(p0 + p1 + bias) ----------------
__global__ __launch_bounds__(256)
void combine_kernel(const float* __restrict__ p0, const float* __restrict__ p1,
                    const float* __restrict__ bias, short* __restrict__ out) {
    const int i = blockIdx.x * 256 + threadIdx.x;
    const long long o = (long long)i * 4;
    const float4 a = *(const float4*)(p0 + o);
    const float4 b = *(const float4*)(p1 + o);
    const int col = (int)(o & (DIM_ - 1));
    const float4 bs = *(const float4*)(bias + col);
    short4 r;
    r.x = f2bf(a.x + b.x + bs.x);
    r.y = f2bf(a.y + b.y + bs.y);
    r.z = f2bf(a.z + b.z + bs.z);
    r.w = f2bf(a.w + b.w + bs.w);
    *(short4*)(out + o) = r;
}

// ---------------- fused per-row top-16 + aggregate (two-phase exact, unchanged R7) ----------------
__global__ __launch_bounds__(256)
void topk_agg_kernel(const float* __restrict__ sim,
                     const float* __restrict__ kcont, const float* __restrict__ wbr,
                     const unsigned short* __restrict__ h, float* __restrict__ y) {
    const int wv = threadIdx.x >> 6;
    const int lane = threadIdx.x & 63;
    const int ll = lane & 15;
    const int row = blockIdx.x * 4 + wv;          // 2048 blocks * 4 waves
    const int b = row >> 10;
    const float* srow = sim + (long long)row * N_;

    float f[16];
    const int base = lane * 16;
#pragma unroll
    for (int q = 0; q < 4; ++q) {
        const float4 v = *(const float4*)(srow + base + q * 4);
        f[q * 4 + 0] = v.x; f[q * 4 + 1] = v.y; f[q * 4 + 2] = v.z; f[q * 4 + 3] = v.w;
    }

    // row max
    float lmax = f[0];
#pragma unroll
    for (int j = 1; j < 16; ++j) lmax = fmaxf(lmax, f[j]);
#pragma unroll
    for (int d = 32; d > 0; d >>= 1) lmax = fmaxf(lmax, __shfl_xor(lmax, d));
    const float maxv = lmax;

    // softmax denominator (full row, exact fp32)
    float lsum = 0.f;
#pragma unroll
    for (int j = 0; j < 16; ++j) lsum += __expf(f[j] - maxv);
#pragma unroll
    for (int d = 32; d > 0; d >>= 1) lsum += __shfl_xor(lsum, d);
    const float invden = 1.f / lsum;

    // ---- Phase A: u32 keys ----
    unsigned key[16];
#pragma unroll
    for (int j = 0; j < 16; ++j)
        key[j] = (f2ord(f[j]) & 0xFFFFFC00u) | (unsigned)(1023 - (base + j));

#pragma unroll
    for (int k = 2; k <= 16; k <<= 1) {
#pragma unroll
        for (int j = k >> 1; j > 0; j >>= 1) {
#pragma unroll
            for (int i = 0; i < 16; ++i) {
                const int l = i ^ j;
                if (l > i) {
                    const bool desc = ((i & k) == 0);
                    const unsigned a = key[i], bk = key[l];
                    const unsigned hi = (a > bk) ? a : bk;
                    const unsigned lo = (a > bk) ? bk : a;
                    key[i] = desc ? hi : lo;
                    key[l] = desc ? lo : hi;
                }
            }
        }
    }

#pragma unroll
    for (int d = 1; d < 64; d <<= 1) {
        unsigned other[16];
#pragma unroll
        for (int i = 0; i < 16; ++i)
            other[i] = __shfl_xor(key[15 - i], d);
#pragma unroll
        for (int i = 0; i < 16; ++i)
            key[i] = (key[i] > other[i]) ? key[i] : other[i];
#pragma unroll
        for (int j = 8; j > 0; j >>= 1) {
#pragma unroll
            for (int i = 0; i < 16; ++i) {
                if ((i & j) == 0) {
                    const unsigned a = key[i], bk = key[i | j];
                    key[i]     = (a > bk) ? a : bk;
                    key[i | j] = (a > bk) ? bk : a;
                }
            }
        }
    }

    // ---- Phase B: exact order of the 16 survivors ----
    unsigned k32 = key[0];
#pragma unroll
    for (int j = 1; j < 16; ++j) k32 = (ll == j) ? key[j] : k32;
    const int myidx = 1023 - (int)(k32 & 1023u);
    const float myval = srow[myidx];

    unsigned long long kx = ((unsigned long long)f2ord(myval) << 32)
                          | (unsigned)(1023 - myidx);
#pragma unroll
    for (int k = 2; k <= 16; k <<= 1) {
#pragma unroll
        for (int d = k >> 1; d > 0; d >>= 1) {
            const unsigned long long other = __shfl_xor(kx, d);
            const bool keepMax = (((ll & k) != 0) == ((ll & d) != 0));
            const bool mineBig = (kx > other);
            kx = (keepMax == mineBig) ? kx : other;
        }
    }
    const unsigned sord = (unsigned)(kx >> 32);
    const unsigned su = (sord & 0x80000000u) ? (sord & 0x7FFFFFFFu) : ~sord;
    const float sval = __uint_as_float(su);
    const int sidx = 1023 - (int)(kx & 1023u);

    const float kc0 = kcont[b * 3 + 0], kc1 = kcont[b * 3 + 1], kc2 = kcont[b * 3 + 2];
    const float w0 = wbr[b * 3 + 0], w1 = wbr[b * 3 + 1], w2 = wbr[b * 3 + 2];

    const float p = __expf(sval - maxv) * invden;
    const float rr = (float)ll + 0.5f;
    const float g0 = sigm(12.f * (kc0 - rr));
    const float g1 = sigm(12.f * (kc1 - rr));
    const float g2 = sigm(12.f * (kc2 - rr));
    float s0 = p * g0, s1 = p * g1, s2 = p * g2;
#pragma unroll
    for (int d = 1; d < 16; d <<= 1) {
        s0 += __shfl_xor(s0, d);
        s1 += __shfl_xor(s1, d);
        s2 += __shfl_xor(s2, d);
    }
    const float f0 = w0 / (s0 + 1e-8f);
    const float f1 = w1 / (s1 + 1e-8f);
    const float f2 = w2 / (s2 + 1e-8f);
    const float mycoef = p * (f0 * g0 + f1 * g1 + f2 * g2);

    const int gbase = lane & 48;
    const unsigned short* hbase = h + (long long)b * (N_ * DIM_) + lane * 8;
    float acc[8] = {0.f, 0.f, 0.f, 0.f, 0.f, 0.f, 0.f, 0.f};
#pragma unroll
    for (int r = 0; r < 16; ++r) {
        const float coef = __shfl(mycoef, gbase | r);
        const int idx = __shfl(sidx, gbase | r);
        const ushort4 h0 = *(const ushort4*)(hbase + (long long)idx * DIM_);
        const ushort4 h1 = *(const ushort4*)(hbase + (long long)idx * DIM_ + 4);
        acc[0] = fmaf(coef, bf2f(h0.x), acc[0]);
        acc[1] = fmaf(coef, bf2f(h0.y), acc[1]);
        acc[2] = fmaf(coef, bf2f(h0.z), acc[2]);
        acc[3] = fmaf(coef, bf2f(h0.w), acc[3]);
        acc[4] = fmaf(coef, bf2f(h1.x), acc[4]);
        acc[5] = fmaf(coef, bf2f(h1.y), acc[5]);
        acc[6] = fmaf(coef, bf2f(h1.z), acc[6]);
        acc[7] = fmaf(coef, bf2f(h1.w), acc[7]);
    }
    float* yp = y + (long long)row * DIM_ + lane * 8;
    *(float4*)(yp + 0) = make_float4(acc[0], acc[1], acc[2], acc[3]);
    *(float4*)(yp + 4) = make_float4(acc[4], acc[5], acc[6], acc[7]);
}

extern "C" void kernel_launch(void* const* d_in, const int* in_sizes, int n_in,
                              void* d_out, int out_size, void* d_ws, size_t ws_size,
                              hipStream_t stream) {
    const float* x     = (const float*)d_in[0];
    const float* fc1_w = (const float*)d_in[1];
    const float* fc1_b = (const float*)d_in[2];
    const float* fc2_w = (const float*)d_in[3];
    const float* fc2_b = (const float*)d_in[4];
    const float* k1_w  = (const float*)d_in[5];
    const float* k1_b  = (const float*)d_in[6];
    const float* k2_w  = (const float*)d_in[7];
    const float* k2_b  = (const float*)d_in[8];
    const float* w1_w  = (const float*)d_in[9];
    const float* w1_b  = (const float*)d_in[10];
    const float* w2_w  = (const float*)d_in[11];
    const float* w2_b  = (const float*)d_in[12];

    char* ws = (char*)d_ws;
    short* h1b    = (short*)(ws + 0);              // 33,554,432
    float* simbuf = (float*)(ws + 0);              // reuse after fc2
    short* xb     = (short*)(ws + 33554432);       // 8,388,608 (dead before partials written)
    float* part0  = (float*)(ws + 33554432);       // 16,777,216
    float* part1  = (float*)(ws + 50331648);       // 16,777,216
    short* hb     = (short*)(ws + 67108864);       // 8,388,608
    short* w1b    = (short*)(ws + 75497472);       // 2,097,152
    short* w2b    = (short*)(ws + 77594624);       // 2,097,152
    float* ppart  = (float*)(ws + 79691776);       // 524,288
    float* kcont  = (float*)(ws + 80216064);       // 128
    float* wbr    = (float*)(ws + 80216192);       // 128

    float* y = (float*)d_out;

    // 0) fused prep: pooled partials + x->bf16 (blocks 0..255), weights->bf16 (256..511)
    prep_kernel<<<dim3(512), dim3(512), 0, stream>>>(x, ppart, xb, fc1_w, fc2_w, w1b, w2b);
    // 1) pooled reduce + head nets
    pool_heads_kernel<<<dim3(B_), dim3(512), 0, stream>>>(ppart, k1_w, k1_b, k2_w, k2_b,
                                                          w1_w, w1_b, w2_w, w2_b, kcont, wbr);
    // 2) h1 = relu(x @ fc1_w^T + b1) -> bf16    M=8192 N=2048 K=512
    gemm_mfma<0><<<dim3(HID_ / 128, ROWS_ / 128, 1), dim3(256), 0, stream>>>(
        xb, w1b, fc1_b, nullptr, h1b, ROWS_, HID_, DIM_, DIM_, DIM_, 0, 0, 0);
    // 3) fc2 split-K=2: partial[z] = h1[:, z*1024:+1024] @ w2[:, z*1024:+1024]^T (fp32 raw)
    gemm_mfma<2><<<dim3(DIM_ / 128, ROWS_ / 128, 2), dim3(256), 0, stream>>>(
        h1b, w2b, nullptr, part0, nullptr, ROWS_, DIM_, HID_ / 2, HID_, HID_,
        (long long)(HID_ / 2), (long long)(HID_ / 2), (long long)ROWS_ * DIM_);
    //    combine: hb = bf16(p0 + p1 + bias)
    combine_kernel<<<dim3(ROWS_ * DIM_ / 4 / 256), dim3(256), 0, stream>>>(part0, part1, fc2_b, hb);
    // 4) sim[b] = hb[b] @ hb[b]^T -> fp32       M=N=1024 K=512, batch 8 (overwrites h1b)
    gemm_mfma<2><<<dim3(N_ / 128, N_ / 128, B_), dim3(256), 0, stream>>>(
        hb, hb, nullptr, simbuf, nullptr, N_, N_, DIM_, DIM_, DIM_,
        (long long)N_ * DIM_, (long long)N_ * DIM_, (long long)N_ * N_);
    // 5) fused per-row top-16 + aggregate into output
    topk_agg_kernel<<<dim3(ROWS_ / 4), dim3(256), 0, stream>>>(
        simbuf, kcont, wbr, (const unsigned short*)hb, y);
}